// Round 12
// baseline (42.849 us; speedup 1.0000x reference)
//
#include <hip/hip_runtime.h>
#include <math.h>

#define BB 32
#define TT 2048
#define CC 128
#define EE 256
#define LL 512
#define TYY 128
#define PP 24
#define NBKT (BB * PP)     // 768 bucket blocks
#define NSIN 256           // sin blocks: 32 b x 8 chunks (256 t)

// ws layout (float-offsets; perm/offs are ints reinterpreted):
//   perm   : int[B][T]     65536  at 0
//   offs   : int[B][32]    1024   at 65536
//   tpart  : [B*8][E]      65536  at 66560
//   cemean : [E]           256    at 132096
//   cbase  : [B][P][C]     98304  at 132352
#define WS_PERM  0
#define WS_OFFS  65536
#define WS_TPART 66560
#define WS_CEM   132096
#define WS_CBASE 132352

// ---------------------------------------------------------------------------
// K0: stable counting-sort permutation of t by phase, per b. grid=B, 256 thr.
// Ballot-based histogram (no atomics): masks[g][w][p] via __ballot; one wave
// computes bucket starts + running (g,w) bases; scatter rank = base + mbcnt.
// Processing order (g, w, lane) == ascending t -> stable.
// ---------------------------------------------------------------------------
__global__ __launch_bounds__(256) void k_perm(const float* __restrict__ ts,
                                              int* __restrict__ perm,
                                              int* __restrict__ offs) {
    __shared__ unsigned long long smask[8][4][PP];
    __shared__ int sbase[8][4][PP];
    __shared__ int soffs[PP + 1];
    const int b = blockIdx.x;
    const int tid = threadIdx.x;
    const int w = tid >> 6;
    const int lane = tid & 63;

    int myp[8];
#pragma unroll
    for (int g = 0; g < 8; ++g) {
        const int t = g * 256 + tid;
        const float v = ts[b * TT + t];
        const int p = ((int)floorf(v)) % PP;       // ts >= 0
        myp[g] = p;
        for (int pp = 0; pp < PP; ++pp) {
            const unsigned long long m = __ballot(p == pp);
            if (lane == 0) smask[g][w][pp] = m;
        }
    }
    __syncthreads();

    if (w == 0 && lane < PP) {
        int tot = 0;
        for (int g = 0; g < 8; ++g)
            for (int ww = 0; ww < 4; ++ww) tot += __popcll(smask[g][ww][lane]);
        int pre = 0;
        for (int q = 0; q < PP; ++q) {
            const int tq = __shfl(tot, q);
            if (q < lane) pre += tq;
        }
        int run = pre;
        for (int g = 0; g < 8; ++g)
            for (int ww = 0; ww < 4; ++ww) {
                sbase[g][ww][lane] = run;
                run += __popcll(smask[g][ww][lane]);
            }
        soffs[lane] = pre;
        if (lane == PP - 1) soffs[PP] = run;       // == TT
    }
    __syncthreads();

#pragma unroll
    for (int g = 0; g < 8; ++g) {
        const int p = myp[g];
        const unsigned long long m = smask[g][w][p];
        const unsigned long long below = (1ull << lane) - 1ull;
        const int rank = sbase[g][w][p] + __popcll(m & below);
        perm[b * TT + rank] = g * 256 + tid;
    }
    if (tid < PP + 1) offs[b * 32 + tid] = soffs[tid];
}

// ---------------------------------------------------------------------------
// K1: heterogeneous, 1025 blocks x 256 thr.
//  [0,768): bucket block (b,p) — segmented streaming sum with REGISTER accs.
//    256 thr = 128 c x 2 row-streams; rows gathered via s_perm (staged LDS);
//    each row read is one coalesced 512B burst. No scatter, no in-loop sync.
//    Writes cbase[b][p][:] = sum/max(cnt,1) directly.
//  [768,1024): sin-pool blocks (pure VALU, overlaps the memory stream).
//  [1024]: channel-embed column mean.
// ---------------------------------------------------------------------------
__global__ __launch_bounds__(256) void k_bucket(const float* __restrict__ ts,
                                                const float* __restrict__ X,
                                                const int*   __restrict__ M,
                                                const int*   __restrict__ perm,
                                                const int*   __restrict__ offs,
                                                const float* __restrict__ tw,
                                                const float* __restrict__ tbias,
                                                const float* __restrict__ ce,
                                                float* __restrict__ cbase,
                                                float* __restrict__ tpart,
                                                float* __restrict__ cemean) {
    const int blk = blockIdx.x;
    const int tid = threadIdx.x;

    if (blk >= NBKT + NSIN) {
        // ---- cemean block ----
        float s = 0.0f;
#pragma unroll 16
        for (int c = 0; c < CC; ++c) s += ce[c * EE + tid];
        cemean[tid] = s * (1.0f / CC);
        return;
    }
    if (blk >= NBKT) {
        // ---- sin-pool block: (b, chunk of 256 t) ----
        __shared__ float s_ts[256];
        const int sb = blk - NBKT;
        const int b = sb >> 3;
        const int chunk = sb & 7;
        s_ts[tid] = ts[b * TT + chunk * 256 + tid];
        __syncthreads();
        const float w = tw[tid];
        const float bb = tbias[tid];
        float a = 0.0f;
#pragma unroll 16
        for (int j = 0; j < 256; ++j) {
            const float v = fmaf(s_ts[j], w, bb);
            a += v + __sinf(v);
        }
        tpart[sb * EE + tid] = a;
        return;
    }

    // ---- bucket block ----
    __shared__ int s_perm[TT];
    __shared__ float2 s_red[256];
    const int b = blk / PP;
    const int p = blk % PP;
    const int start = offs[b * 32 + p];
    const int end   = offs[b * 32 + p + 1];
    const int cnt   = end - start;
    const int c  = tid & 127;
    const int th = tid >> 7;                       // 0/1 row-stream

    for (int i = tid; i < cnt; i += 256) s_perm[i] = perm[b * TT + start + i];
    __syncthreads();

    float s = 0.0f, n = 0.0f;
    int i = th;
    for (; i + 16 <= cnt; i += 16) {               // 8 rows deep per stream
        float xv[8]; int mv[8];
#pragma unroll
        for (int k = 0; k < 8; ++k) {
            const int t = s_perm[i + 2 * k];
            const long r = ((long)(b * TT + t)) * CC + c;
            xv[k] = X[r];
            mv[k] = M[r];
        }
#pragma unroll
        for (int k = 0; k < 8; ++k) {
            const float m = (float)mv[k];
            s = fmaf(xv[k], m, s);
            n += m;
        }
    }
    for (; i < cnt; i += 2) {
        const int t = s_perm[i];
        const long r = ((long)(b * TT + t)) * CC + c;
        const float m = (float)M[r];
        s = fmaf(X[r], m, s);
        n += m;
    }

    s_red[tid] = make_float2(s, n);
    __syncthreads();
    if (tid < 128) {
        const float2 a = s_red[tid];
        const float2 d = s_red[tid + 128];
        cbase[(b * PP + p) * CC + tid] = (a.x + d.x) / fmaxf(a.y + d.y, 1.0f);
    }
}

// ---------------------------------------------------------------------------
// K2: decoder MLP + output scatter. grid = B (32), block = 1024.
// ---------------------------------------------------------------------------
__global__ __launch_bounds__(1024) void k_tail(const float* __restrict__ tpart,
                                               const float* __restrict__ cemean,
                                               const float* __restrict__ w1,
                                               const float* __restrict__ b1,
                                               const float* __restrict__ w2,
                                               const float* __restrict__ b2,
                                               const float* __restrict__ cbase,
                                               const float* __restrict__ yt,
                                               float* __restrict__ out) {
    __shared__ float s_pool[EE];
    __shared__ float s_h[LL];
    __shared__ float s_part[1024];
    __shared__ float s_cb[PP * CC];
    __shared__ float s_y[CC];
    const int b = blockIdx.x;
    const int tid = threadIdx.x;

    for (int i = tid; i < PP * CC; i += 1024) s_cb[i] = cbase[b * PP * CC + i];

    if (tid < EE) {
        float sp = 0.0f;
#pragma unroll
        for (int k = 0; k < 8; ++k) sp += tpart[(b * 8 + k) * EE + tid];
        s_pool[tid] = sp * (1.0f / TT) + cemean[tid];
    }
    __syncthreads();

    {
        const int l = tid & 511;
        const int hh = tid >> 9;
        float ha = 0.0f;
#pragma unroll 16
        for (int e = hh * 128; e < hh * 128 + 128; ++e)
            ha = fmaf(s_pool[e], w1[e * LL + l], ha);
        s_part[tid] = ha;
    }
    __syncthreads();
    if (tid < LL)
        s_h[tid] = fmaxf(b1[tid] + s_part[tid] + s_part[tid + 512], 0.0f);
    __syncthreads();

    {
        const int c = tid & 127;
        const int q8 = tid >> 7;
        float y = 0.0f;
#pragma unroll 16
        for (int l = q8 * 64; l < q8 * 64 + 64; ++l)
            y = fmaf(s_h[l], w2[l * CC + c], y);
        s_part[tid] = y;
    }
    __syncthreads();
    if (tid < CC) {
        float y = b2[tid];
#pragma unroll
        for (int i = 0; i < 8; ++i) y += s_part[tid + 128 * i];
        s_y[tid] = y;
    }
    __syncthreads();

    for (int i = tid; i < TYY * CC; i += 1024) {
        const int ty = i >> 7;
        const int c = i & 127;
        const float v = yt[b * TYY + ty];
        int p = ((int)floorf(v)) % PP; if (p < 0) p += PP;
        out[((long)(b * TYY + ty)) * CC + c] = s_y[c] + s_cb[p * CC + c];
    }
}

extern "C" void kernel_launch(void* const* d_in, const int* in_sizes, int n_in,
                              void* d_out, int out_size, void* d_ws, size_t ws_size,
                              hipStream_t stream) {
    const float* ts   = (const float*)d_in[0];
    const float* X    = (const float*)d_in[1];
    const int*   M    = (const int*)  d_in[2];
    const float* yt   = (const float*)d_in[3];
    const float* tw   = (const float*)d_in[4];
    const float* tb   = (const float*)d_in[5];
    const float* ce   = (const float*)d_in[6];
    const float* w1   = (const float*)d_in[7];
    const float* b1   = (const float*)d_in[8];
    const float* w2   = (const float*)d_in[9];
    const float* b2   = (const float*)d_in[10];
    float* out = (float*)d_out;

    float* ws     = (float*)d_ws;
    int*   perm   = (int*)(ws + WS_PERM);
    int*   offs   = (int*)(ws + WS_OFFS);
    float* tpart  = ws + WS_TPART;
    float* cemean = ws + WS_CEM;
    float* cbase  = ws + WS_CBASE;

    k_perm<<<BB, 256, 0, stream>>>(ts, perm, offs);
    k_bucket<<<NBKT + NSIN + 1, 256, 0, stream>>>(ts, X, M, perm, offs, tw, tb,
                                                  ce, cbase, tpart, cemean);
    k_tail<<<BB, 1024, 0, stream>>>(tpart, cemean, w1, b1, w2, b2, cbase, yt, out);
}